// Round 9
// baseline (2254.396 us; speedup 1.0000x reference)
//
#include <hip/hip_runtime.h>

typedef __attribute__((ext_vector_type(8))) _Float16 half8;
typedef __attribute__((ext_vector_type(4))) _Float16 half4;
typedef __attribute__((ext_vector_type(4))) float f32x4;

#define N_NODES 6272
#define CDIM    2048
#define ODIM    512
#define NTIL    49       // 6272 / 128 exactly (both dims)
#define NSLOT   392      // 49 tiles * 8 candidates per node
#define GRID_G  2401     // 49*49

// ---------------- workspace layout (bytes) ----------------
#define XHI_OFF    0ul
#define XLO_OFF    25690112ul
#define CANDV_OFF  51380224ul          // 6272*392*4  = 9,834,496
#define CANDI_OFF  61214720ul          // 6272*392*2  = 4,917,248 (u16)
#define SQ_OFF     66131968ul
#define KNN_OFF    66157056ul
#define DEG_OFF    66357760ul
#define CNT_OFF    66382848ul
#define DINV_OFF   66407936ul
#define RPTR_OFF   66433024ul
#define COL_OFF    66458368ul
#define W1T_OFF    66684160ul
#define W2T_OFF    68781312ul          // end 69,305,600
// hw (f32, 12.8MB) and h1h (fp16, 6.4MB) reuse the XLO region after gram is done
#define HW_OFF     XLO_OFF
#define H1H_OFF    (XLO_OFF + 12845056ul)

// ---------------- async global->LDS (16B per lane, wave-uniform LDS base) ----
__device__ __forceinline__ void gld_lds16(const void* g, void* l) {
    __builtin_amdgcn_global_load_lds(
        (const __attribute__((address_space(1))) void*)g,
        (__attribute__((address_space(3))) void*)l, 16, 0, 0);
}

// BK=64 tile: [row][128B]; 16B slot b holds global k-block b ^ (row&7).
__device__ __forceinline__ half8 frag_read(const char* base, int row, int s, int lane) {
    int b = (s * 4 + (lane >> 4)) ^ (row & 7);
    return *(const half8*)(base + row * 128 + b * 16);
}

#define MF(a, b, c) __builtin_amdgcn_mfma_f32_16x16x32_f16(a, b, c, 0, 0, 0)

// ---------------- x -> (hi, lo) fp16 split ----------------
__global__ __launch_bounds__(256) void conv_split_kernel(const float* __restrict__ x,
        _Float16* __restrict__ xhi, _Float16* __restrict__ xlo) {
    size_t idx = ((size_t)blockIdx.x * 256 + threadIdx.x) * 4;
    float4 v = *(const float4*)(x + idx);
    float vv[4] = {v.x, v.y, v.z, v.w};
    half4 h, l;
#pragma unroll
    for (int j = 0; j < 4; j++) {
        _Float16 hj = (_Float16)vv[j];
        h[j] = hj;
        l[j] = (_Float16)(vv[j] - (float)hj);
    }
    *(half4*)(xhi + idx) = h;
    *(half4*)(xlo + idx) = l;
}

// ---------------- W [K][N] f32 -> Wt [N][K] f16 ----------------
__global__ __launch_bounds__(256) void wtrans_kernel(const float* __restrict__ W,
        _Float16* __restrict__ Wt, int K, int N) {
    __shared__ float tile[64][65];
    int kb = blockIdx.x * 64, nb = blockIdx.y * 64;
    int tid = threadIdx.x;
    int r = tid >> 2, c0 = (tid & 3) * 16;
#pragma unroll
    for (int u = 0; u < 4; u++) {
        float4 v = *(const float4*)(W + (size_t)(kb + r) * N + nb + c0 + u * 4);
        tile[r][c0 + u * 4 + 0] = v.x; tile[r][c0 + u * 4 + 1] = v.y;
        tile[r][c0 + u * 4 + 2] = v.z; tile[r][c0 + u * 4 + 3] = v.w;
    }
    __syncthreads();
    int rn = tid >> 2, ck0 = (tid & 3) * 16;
#pragma unroll
    for (int u = 0; u < 4; u++) {
        half4 o;
#pragma unroll
        for (int j = 0; j < 4; j++) o[j] = (_Float16)tile[ck0 + u * 4 + j][rn];
        *(half4*)(Wt + (size_t)(nb + rn) * K + kb + ck0 + u * 4) = o;
    }
}

// ---------------- sq[i] = sum_c x[i][c]^2 (fp32, exact vs ref) ----------------
__global__ __launch_bounds__(64) void sq_kernel(const float* __restrict__ x,
                                                float* __restrict__ sq) {
    int i = blockIdx.x;
    int t = threadIdx.x;
    const float* row = x + (size_t)i * CDIM;
    float s = 0.f;
#pragma unroll
    for (int k = 0; k < CDIM / 256; k++) {
        float4 v = *(const float4*)(row + (k * 64 + t) * 4);
        s += v.x * v.x + v.y * v.y + v.z * v.z + v.w * v.w;
    }
#pragma unroll
    for (int off = 32; off; off >>= 1) s += __shfl_down(s, off, 64);
    if (t == 0) sq[i] = s;
}

// ---------- fused MFMA Gram (128x128 tiles, BK=64, true dbuf) + row top-8 ----------
// dot = hi.hi + hi.lo + lo.hi ; grid = 2401, 512 threads (8 waves: wr=wave>>2 in
// 0..1 x 64 rows, wc=wave&3 in 0..3 x 32 cols; acc[4][2] = 32 VGPR).
// K-loop per chunk: issue 8 gld_lds (contiguous 1KB each, 128B/row granule) for
// chunk c+1 -> s_waitcnt vmcnt(8) (counts THIS wave's outstanding; never drains
// the pipe) -> raw s_barrier -> MFMA on chunk c -> s_barrier. No __syncthreads
// in the loop (it would drain vmcnt(0) and kill the prefetch).
// All acc[][] indices compile-time (rule #20).
__global__ __launch_bounds__(512, 2) void gram_topk_mfma(
        const _Float16* __restrict__ xhi, const _Float16* __restrict__ xlo,
        const float* __restrict__ sq,
        float* __restrict__ candv, unsigned short* __restrict__ candi) {
    __shared__ char lds[131072];              // 2 x 64KB {Ahi,Alo,Bhi,Blo x 16KB}
    __shared__ float topv[128][9];
    __shared__ unsigned short topi[128][10];

    int tid = threadIdx.x, lane = tid & 63, wave = tid >> 6;
    int wr = wave >> 2, wc = wave & 3;
    int l15 = lane & 15, kg = lane >> 4;

    // bijective XCD swizzle over 2401 = 8*300 + 1
    int bid = blockIdx.x;
    int xcd = bid & 7, loc = bid >> 3;
    int swz = (xcd < 1) ? loc : (301 + (xcd - 1) * 300 + loc);
    int p = swz / NTIL, t = swz % NTIL;
    size_t i0 = (size_t)p * 128, j0 = (size_t)t * 128;

    if (tid < 128) {
#pragma unroll
        for (int k = 0; k < 8; k++) { topv[tid][k] = 3.4e38f; topi[tid][k] = 0xFFFF; }
    }
    __syncthreads();   // nothing outstanding yet; topv visible

    f32x4 acc[4][2] = {};

    // per-wave staging: 8 segs (seg = 8 rows x 128B = 1KB contiguous, lanes monotonic
    // within 128B up to the (l&7)^(row&7) block swizzle matching frag_read)
    int srow_in = lane >> 3;                   // 0..7
    int skb = (lane & 7) ^ srow_in;            // pre-swizzled 16B block id

#define STAGE_CHUNK(BUF, KK) do {                                              \
    _Pragma("unroll")                                                          \
    for (int g = 0; g < 8; g++) {                                              \
        int sg = wave * 8 + g;                                                 \
        int tIdx = sg >> 4, seg = sg & 15;                                     \
        const _Float16* src = (tIdx & 1) ? xlo : xhi;                          \
        size_t rbase = (tIdx < 2) ? i0 : j0;                                   \
        int R = seg * 8;                                                       \
        gld_lds16(src + (rbase + (size_t)(R + srow_in)) * CDIM + (KK) + skb * 8,\
                  (BUF) + tIdx * 16384 + R * 128);                             \
    }                                                                          \
} while (0)

    STAGE_CHUNK(lds, 0);

#pragma unroll 1
    for (int c = 0; c < 32; c++) {
        char* cur = (c & 1) ? lds + 65536 : lds;
        char* nxt = (c & 1) ? lds : lds + 65536;
        if (c < 31) {
            STAGE_CHUNK(nxt, (c + 1) * 64);
            asm volatile("s_waitcnt vmcnt(8)" ::: "memory");
        } else {
            asm volatile("s_waitcnt vmcnt(0)" ::: "memory");
        }
        __builtin_amdgcn_sched_barrier(0);
        __builtin_amdgcn_s_barrier();
        __builtin_amdgcn_sched_barrier(0);
#pragma unroll
        for (int s = 0; s < 2; s++) {
            half8 ah[4], al[4];
#pragma unroll
            for (int m = 0; m < 4; m++) ah[m] = frag_read(cur,         wr * 64 + m * 16 + l15, s, lane);
#pragma unroll
            for (int m = 0; m < 4; m++) al[m] = frag_read(cur + 16384, wr * 64 + m * 16 + l15, s, lane);
#pragma unroll
            for (int n = 0; n < 2; n++) {
                half8 bh = frag_read(cur + 32768, wc * 32 + n * 16 + l15, s, lane);
                half8 bl = frag_read(cur + 49152, wc * 32 + n * 16 + l15, s, lane);
#pragma unroll
                for (int m = 0; m < 4; m++) acc[m][n] = MF(ah[m], bh, acc[m][n]);
#pragma unroll
                for (int m = 0; m < 4; m++) acc[m][n] = MF(al[m], bh, acc[m][n]);
#pragma unroll
                for (int m = 0; m < 4; m++) acc[m][n] = MF(ah[m], bl, acc[m][n]);
            }
        }
        __builtin_amdgcn_sched_barrier(0);
        __builtin_amdgcn_s_barrier();
    }

    // sq values (after K-loop; no guards needed: 6272 = 49*128 exactly)
    float sqi[4][4];
#pragma unroll
    for (int m = 0; m < 4; m++)
#pragma unroll
        for (int r = 0; r < 4; r++)
            sqi[m][r] = sq[(int)i0 + wr * 64 + m * 16 + kg * 4 + r];
    float sqj[2];
#pragma unroll
    for (int n = 0; n < 2; n++)
        sqj[n] = sq[(int)j0 + wc * 32 + n * 16 + l15];

    // ---- epilogue: d2 -> S (32-col chunks), per-row serial top-8 ----
    float* S = (float*)lds;   // [128][33]
#pragma unroll
    for (int cs = 0; cs < 4; cs++) {
        __syncthreads();
        if (wc == cs) {
#pragma unroll
            for (int m = 0; m < 4; m++)
#pragma unroll
                for (int n = 0; n < 2; n++)
#pragma unroll
                    for (int r = 0; r < 4; r++) {
                        int row = wr * 64 + m * 16 + kg * 4 + r;
                        float d2 = sqi[m][r] + sqj[n] - 2.f * acc[m][n][r];
                        S[row * 33 + n * 16 + l15] = d2;
                    }
        }
        __syncthreads();
        if (tid < 128) {
            int r = tid, gi = (int)i0 + r;
            int cbase = (int)j0 + cs * 32;
#pragma unroll 4
            for (int jj = 0; jj < 32; jj++) {
                int gj = cbase + jj;
                if (gj == gi) continue;
                float v = S[r * 33 + jj];
                float wv = topv[r][7]; int wi = topi[r][7];
                if (v < wv || (v == wv && gj < wi)) {
                    int pos = 7;
                    while (pos > 0) {
                        float pv = topv[r][pos - 1]; int pi = topi[r][pos - 1];
                        if (v < pv || (v == pv && gj < pi)) {
                            topv[r][pos] = pv; topi[r][pos] = (unsigned short)pi; pos--;
                        } else break;
                    }
                    topv[r][pos] = v; topi[r][pos] = (unsigned short)gj;
                }
            }
        }
    }
    __syncthreads();
    if (tid < 128) {
        int gi = (int)i0 + tid;
#pragma unroll
        for (int k = 0; k < 8; k++) {
            candv[(size_t)gi * NSLOT + t * 8 + k] = topv[tid][k];
            candi[(size_t)gi * NSLOT + t * 8 + k] = topi[tid][k];
        }
    }
#undef STAGE_CHUNK
}

// ------------- merge 49 sorted 8-lists -> knn (wave per node, lex (v,idx)) -----
__global__ __launch_bounds__(256) void merge_topk_kernel(
        const float* __restrict__ candv, const unsigned short* __restrict__ candi,
        int* __restrict__ knn) {
    int node = blockIdx.x * 4 + (threadIdx.x >> 6);
    int lane = threadIdx.x & 63;
    const float* cv = candv + (size_t)node * NSLOT;
    const unsigned short* ci = candi + (size_t)node * NSLOT;
    float v[7]; int ix[7];
#pragma unroll
    for (int u = 0; u < 7; u++) {
        int s = u * 64 + lane;
        bool ok = (s < NSLOT);
        v[u]  = ok ? cv[s] : 3.4e38f;
        ix[u] = ok ? (int)ci[s] : 0x7fffffff;
    }
#pragma unroll 1
    for (int k = 0; k < 8; k++) {
        float bv = v[0]; int bi = ix[0];
#pragma unroll
        for (int u = 1; u < 7; u++)
            if (v[u] < bv || (v[u] == bv && ix[u] < bi)) { bv = v[u]; bi = ix[u]; }
#pragma unroll
        for (int off = 32; off; off >>= 1) {
            float ov = __shfl_xor(bv, off, 64);
            int   oi = __shfl_xor(bi, off, 64);
            if (ov < bv || (ov == bv && oi < bi)) { bv = ov; bi = oi; }
        }
        if (lane == 0) knn[(size_t)node * 8 + k] = bi;
#pragma unroll
        for (int u = 0; u < 7; u++)
            if (ix[u] == bi) { v[u] = 3.4e38f; ix[u] = 0x7fffffff; }
    }
}

// ------------- graph build -------------
__global__ __launch_bounds__(256) void graph_init_kernel(int* deg, int* cnt) {
    int i = blockIdx.x * 256 + threadIdx.x;
    if (i < N_NODES) { deg[i] = 1; cnt[i] = 0; }
}
__global__ __launch_bounds__(256) void deg_count_kernel(const int* __restrict__ knn,
                                                        int* deg) {
    int e = blockIdx.x * 256 + threadIdx.x;
    if (e < N_NODES * 8) atomicAdd(&deg[knn[e]], 1);
}
__global__ __launch_bounds__(256) void dinv_kernel(const int* __restrict__ deg,
                                                   float* __restrict__ dinv) {
    int i = blockIdx.x * 256 + threadIdx.x;
    if (i < N_NODES) dinv[i] = rsqrtf((float)deg[i]);
}
__global__ __launch_bounds__(256) void scan_kernel(const int* __restrict__ deg,
                                                   int* __restrict__ row_ptr) {
    __shared__ int partial[256];
    const int CHUNK = (N_NODES + 255) / 256;
    int tid = threadIdx.x;
    int start = tid * CHUNK;
    int end = start + CHUNK; if (end > N_NODES) end = N_NODES;
    int s = 0;
    for (int i = start; i < end; i++) s += deg[i];
    partial[tid] = s;
    __syncthreads();
    if (tid == 0) {
        int run = 0;
        for (int k = 0; k < 256; k++) { int v = partial[k]; partial[k] = run; run += v; }
        row_ptr[N_NODES] = run;
    }
    __syncthreads();
    int run = partial[tid];
    for (int i = start; i < end; i++) { row_ptr[i] = run; run += deg[i]; }
}
__global__ __launch_bounds__(256) void scatter_kernel(const int* __restrict__ knn,
        const int* __restrict__ row_ptr, int* cnt, int* __restrict__ col) {
    int i = blockIdx.x * 256 + threadIdx.x;
    if (i >= N_NODES) return;
    int ptr = row_ptr[i] + atomicAdd(&cnt[i], 1);
    col[ptr] = i;                                   // self-loop
#pragma unroll
    for (int j = 0; j < 8; j++) {
        int d = knn[(size_t)i * 8 + j];
        int q = row_ptr[d] + atomicAdd(&cnt[d], 1);
        col[q] = i;
    }
}

// ------------- fp16 MFMA GEMM  C[M,N] = A[M,K] @ Bt[N,K]^T  (f32 out) --------
__global__ __launch_bounds__(256) void hgemm_nt_kernel(
        const _Float16* __restrict__ A, const _Float16* __restrict__ Bt,
        float* __restrict__ C, int M, int N, int K) {
    __shared__ char Alds[16384], Blds[16384];
    int tid = threadIdx.x, lane = tid & 63, wave = tid >> 6;
    int wr = wave >> 1, wc = wave & 1;
    int l15 = lane & 15, kg = lane >> 4;
    int nt = N >> 7;
    int i0 = (blockIdx.x / nt) * 128, j0 = (blockIdx.x % nt) * 128;
    f32x4 acc[4][4] = {};

#pragma unroll 1
    for (int kk = 0; kk < K; kk += 64) {
        __syncthreads();
#pragma unroll
        for (int g = 0; g < 4; g++) {
            int R = wave * 32 + g * 8;
            int swzk = ((lane & 7) ^ (lane >> 3)) << 3;
            const _Float16* ga = A + (size_t)(i0 + R + (lane >> 3)) * K + kk + swzk;
            gld_lds16(ga, Alds + R * 128);
            const _Float16* gb = Bt + (size_t)(j0 + R + (lane >> 3)) * K + kk + swzk;
            gld_lds16(gb, Blds + R * 128);
        }
        __syncthreads();
#pragma unroll
        for (int s = 0; s < 2; s++) {
            half8 a[4], b[4];
#pragma unroll
            for (int m = 0; m < 4; m++) a[m] = frag_read(Alds, wr * 64 + m * 16 + l15, s, lane);
#pragma unroll
            for (int n = 0; n < 4; n++) b[n] = frag_read(Blds, wc * 64 + n * 16 + l15, s, lane);
#pragma unroll
            for (int m = 0; m < 4; m++)
#pragma unroll
                for (int n = 0; n < 4; n++)
                    acc[m][n] = __builtin_amdgcn_mfma_f32_16x16x32_f16(a[m], b[n], acc[m][n], 0, 0, 0);
        }
    }
#pragma unroll
    for (int m = 0; m < 4; m++)
#pragma unroll
        for (int n = 0; n < 4; n++)
#pragma unroll
            for (int r = 0; r < 4; r++) {
                int row = i0 + wr * 64 + m * 16 + kg * 4 + r;
                int colj = j0 + wc * 64 + n * 16 + l15;
                C[(size_t)row * N + colj] = acc[m][n][r];
            }
}

// ------------- GCN aggregation: out[d] = relu(dinv[d]*sum hw[s]*dinv[s] + b) ---
template <bool HALF>
__global__ __launch_bounds__(256) void aggregate_kernel(
        const float* __restrict__ hw, const int* __restrict__ row_ptr,
        const int* __restrict__ col, const float* __restrict__ dinv,
        const float* __restrict__ bias, void* __restrict__ outp) {
    int node = blockIdx.x * 4 + (threadIdx.x >> 6);
    int lane = threadIdx.x & 63;
    int e0 = row_ptr[node], e1 = row_ptr[node + 1];
    float4 acc0 = {0.f, 0.f, 0.f, 0.f}, acc1 = {0.f, 0.f, 0.f, 0.f};
    for (int e = e0; e < e1; e++) {
        int s = col[e];
        float w = dinv[s];
        const float* hr = hw + (size_t)s * ODIM;
        float4 v0 = *(const float4*)(hr + lane * 4);
        float4 v1 = *(const float4*)(hr + 256 + lane * 4);
        acc0.x = fmaf(w, v0.x, acc0.x); acc0.y = fmaf(w, v0.y, acc0.y);
        acc0.z = fmaf(w, v0.z, acc0.z); acc0.w = fmaf(w, v0.w, acc0.w);
        acc1.x = fmaf(w, v1.x, acc1.x); acc1.y = fmaf(w, v1.y, acc1.y);
        acc1.z = fmaf(w, v1.z, acc1.z); acc1.w = fmaf(w, v1.w, acc1.w);
    }
    float wd = dinv[node];
    float4 b0 = *(const float4*)(bias + lane * 4);
    float4 b1 = *(const float4*)(bias + 256 + lane * 4);
    float o[8];
    o[0] = fmaxf(fmaf(acc0.x, wd, b0.x), 0.f);
    o[1] = fmaxf(fmaf(acc0.y, wd, b0.y), 0.f);
    o[2] = fmaxf(fmaf(acc0.z, wd, b0.z), 0.f);
    o[3] = fmaxf(fmaf(acc0.w, wd, b0.w), 0.f);
    o[4] = fmaxf(fmaf(acc1.x, wd, b1.x), 0.f);
    o[5] = fmaxf(fmaf(acc1.y, wd, b1.y), 0.f);
    o[6] = fmaxf(fmaf(acc1.z, wd, b1.z), 0.f);
    o[7] = fmaxf(fmaf(acc1.w, wd, b1.w), 0.f);
    if (HALF) {
        _Float16* out = (_Float16*)outp;
        half4 h0, h1;
#pragma unroll
        for (int j = 0; j < 4; j++) { h0[j] = (_Float16)o[j]; h1[j] = (_Float16)o[4 + j]; }
        *(half4*)(out + (size_t)node * ODIM + lane * 4)       = h0;
        *(half4*)(out + (size_t)node * ODIM + 256 + lane * 4) = h1;
    } else {
        float* out = (float*)outp;
        float4 f0 = {o[0], o[1], o[2], o[3]}, f1 = {o[4], o[5], o[6], o[7]};
        *(float4*)(out + (size_t)node * ODIM + lane * 4)       = f0;
        *(float4*)(out + (size_t)node * ODIM + 256 + lane * 4) = f1;
    }
}

extern "C" void kernel_launch(void* const* d_in, const int* in_sizes, int n_in,
                              void* d_out, int out_size, void* d_ws, size_t ws_size,
                              hipStream_t stream) {
    const float* x  = (const float*)d_in[0];
    const float* W1 = (const float*)d_in[1];
    const float* b1 = (const float*)d_in[2];
    const float* W2 = (const float*)d_in[3];
    const float* b2 = (const float*)d_in[4];
    float* out = (float*)d_out;
    char* ws = (char*)d_ws;

    _Float16* xhi  = (_Float16*)(ws + XHI_OFF);
    _Float16* xlo  = (_Float16*)(ws + XLO_OFF);
    float* candv   = (float*)(ws + CANDV_OFF);
    unsigned short* candi = (unsigned short*)(ws + CANDI_OFF);
    float* sq      = (float*)(ws + SQ_OFF);
    int*   knn     = (int*)  (ws + KNN_OFF);
    int*   deg     = (int*)  (ws + DEG_OFF);
    int*   cnt     = (int*)  (ws + CNT_OFF);
    float* dinv    = (float*)(ws + DINV_OFF);
    int*   row_ptr = (int*)  (ws + RPTR_OFF);
    int*   col     = (int*)  (ws + COL_OFF);
    _Float16* w1t  = (_Float16*)(ws + W1T_OFF);
    _Float16* w2t  = (_Float16*)(ws + W2T_OFF);
    float* hw      = (float*)(ws + HW_OFF);       // reuses xlo region (post-gram)
    _Float16* h1h  = (_Float16*)(ws + H1H_OFF);   // reuses xlo region (post-gram)

    conv_split_kernel<<<12544, 256, 0, stream>>>(x, xhi, xlo);
    sq_kernel<<<N_NODES, 64, 0, stream>>>(x, sq);
    wtrans_kernel<<<dim3(CDIM / 64, ODIM / 64), 256, 0, stream>>>(W1, w1t, CDIM, ODIM);
    wtrans_kernel<<<dim3(ODIM / 64, ODIM / 64), 256, 0, stream>>>(W2, w2t, ODIM, ODIM);

    gram_topk_mfma<<<GRID_G, 512, 0, stream>>>(xhi, xlo, sq, candv, candi);
    merge_topk_kernel<<<N_NODES / 4, 256, 0, stream>>>(candv, candi, knn);

    graph_init_kernel<<<(N_NODES + 255) / 256, 256, 0, stream>>>(deg, cnt);
    deg_count_kernel<<<(N_NODES * 8) / 256, 256, 0, stream>>>(knn, deg);
    dinv_kernel<<<(N_NODES + 255) / 256, 256, 0, stream>>>(deg, dinv);
    scan_kernel<<<1, 256, 0, stream>>>(deg, row_ptr);
    scatter_kernel<<<(N_NODES + 255) / 256, 256, 0, stream>>>(knn, row_ptr, cnt, col);

    hgemm_nt_kernel<<<(N_NODES / 128) * (ODIM / 128), 256, 0, stream>>>(xhi, w1t, hw, N_NODES, ODIM, CDIM);
    aggregate_kernel<true><<<N_NODES / 4, 256, 0, stream>>>(hw, row_ptr, col, dinv, b1, (void*)h1h);
    hgemm_nt_kernel<<<(N_NODES / 128) * (ODIM / 128), 256, 0, stream>>>(h1h, w2t, hw, N_NODES, ODIM, ODIM);
    aggregate_kernel<false><<<N_NODES / 4, 256, 0, stream>>>(hw, row_ptr, col, dinv, b2, (void*)out);
}

// Round 10
// 1731.375 us; speedup vs baseline: 1.3021x; 1.3021x over previous
//
#include <hip/hip_runtime.h>

typedef __attribute__((ext_vector_type(8))) _Float16 half8;
typedef __attribute__((ext_vector_type(4))) _Float16 half4;
typedef __attribute__((ext_vector_type(4))) float f32x4;

#define N_NODES 6272
#define CDIM    2048
#define ODIM    512
#define NT      25       // 256-node panels (ceil 6272/256)
#define NSLOT   200      // 25 panels * 8 candidates per node
#define GRID_G  352      // 8 XCDs x 44 (325 live triangle tiles + 27 dead)

// ---------------- workspace layout (bytes) ----------------
#define XHI_OFF    0ul
#define XLO_OFF    25690112ul
#define CANDV_OFF  51380224ul
#define CANDI_OFF  56397824ul
#define SQ_OFF     61415424ul
#define KNN_OFF    61440512ul
#define DEG_OFF    61641216ul
#define CNT_OFF    61666304ul
#define DINV_OFF   61691392ul
#define RPTR_OFF   61716480ul
#define COL_OFF    61741824ul
#define W1T_OFF    61967616ul
#define W2T_OFF    64064768ul
// hw (f32, 12.8MB) and h1h (fp16, 6.4MB) reuse the XLO region after gram is done
#define HW_OFF     XLO_OFF
#define H1H_OFF    (XLO_OFF + 12845056ul)

// ---------------- async global->LDS (16B per lane, wave-uniform LDS base) ----
__device__ __forceinline__ void gld_lds16(const void* g, void* l) {
    __builtin_amdgcn_global_load_lds(
        (const __attribute__((address_space(1))) void*)g,
        (__attribute__((address_space(3))) void*)l, 16, 0, 0);
}

// BK=64 tile: [row][128B]; 16B slot b holds global k-block b ^ (row&7).
__device__ __forceinline__ half8 frag_read(const char* base, int row, int s, int lane) {
    int b = (s * 4 + (lane >> 4)) ^ (row & 7);
    return *(const half8*)(base + row * 128 + b * 16);
}

#define MF(a, b, c) __builtin_amdgcn_mfma_f32_16x16x32_f16(a, b, c, 0, 0, 0)

// ---------------- x -> (hi, lo) fp16 split ----------------
__global__ __launch_bounds__(256) void conv_split_kernel(const float* __restrict__ x,
        _Float16* __restrict__ xhi, _Float16* __restrict__ xlo) {
    size_t idx = ((size_t)blockIdx.x * 256 + threadIdx.x) * 4;
    float4 v = *(const float4*)(x + idx);
    float vv[4] = {v.x, v.y, v.z, v.w};
    half4 h, l;
#pragma unroll
    for (int j = 0; j < 4; j++) {
        _Float16 hj = (_Float16)vv[j];
        h[j] = hj;
        l[j] = (_Float16)(vv[j] - (float)hj);
    }
    *(half4*)(xhi + idx) = h;
    *(half4*)(xlo + idx) = l;
}

// ---------------- W [K][N] f32 -> Wt [N][K] f16 ----------------
__global__ __launch_bounds__(256) void wtrans_kernel(const float* __restrict__ W,
        _Float16* __restrict__ Wt, int K, int N) {
    __shared__ float tile[64][65];
    int kb = blockIdx.x * 64, nb = blockIdx.y * 64;
    int tid = threadIdx.x;
    int r = tid >> 2, c0 = (tid & 3) * 16;
#pragma unroll
    for (int u = 0; u < 4; u++) {
        float4 v = *(const float4*)(W + (size_t)(kb + r) * N + nb + c0 + u * 4);
        tile[r][c0 + u * 4 + 0] = v.x; tile[r][c0 + u * 4 + 1] = v.y;
        tile[r][c0 + u * 4 + 2] = v.z; tile[r][c0 + u * 4 + 3] = v.w;
    }
    __syncthreads();
    int rn = tid >> 2, ck0 = (tid & 3) * 16;
#pragma unroll
    for (int u = 0; u < 4; u++) {
        half4 o;
#pragma unroll
        for (int j = 0; j < 4; j++) o[j] = (_Float16)tile[ck0 + u * 4 + j][rn];
        *(half4*)(Wt + (size_t)(nb + rn) * K + kb + ck0 + u * 4) = o;
    }
}

// ---------------- sq[i] = sum_c x[i][c]^2 (fp32, exact vs ref) ----------------
__global__ __launch_bounds__(64) void sq_kernel(const float* __restrict__ x,
                                                float* __restrict__ sq) {
    int i = blockIdx.x;
    int t = threadIdx.x;
    const float* row = x + (size_t)i * CDIM;
    float s = 0.f;
#pragma unroll
    for (int k = 0; k < CDIM / 256; k++) {
        float4 v = *(const float4*)(row + (k * 64 + t) * 4);
        s += v.x * v.x + v.y * v.y + v.z * v.z + v.w * v.w;
    }
#pragma unroll
    for (int off = 32; off; off >>= 1) s += __shfl_down(s, off, 64);
    if (t == 0) sq[i] = s;
}

// ---- fused MFMA Gram: upper-triangle 256x256 tiles, row+col top-8 extraction ----
// dot = hi.hi + hi.lo + lo.hi. Miss-byte minimization:
//  * triangle (325 tiles) halves staged bytes vs full grid (r5-verified dual pass);
//  * serpentine column->XCD dealing + xcd=bid&7 inversion keeps each XCD's ~32
//    concurrent blocks within 1-2 t-columns -> B panels (2-4MB) stay L2-resident;
//    A panels stream (the unavoidable ~650MB of L2-miss traffic).
//  * staging is BK=64 / 128B-per-row full-cache-line segs (r9-verified granule).
// Single-buffered (r4 showed overlap does not change the miss-path delivery rate).
// All acc[][] indices compile-time (rule #20).
__global__ __launch_bounds__(512, 2) void gram_topk_mfma(
        const _Float16* __restrict__ xhi, const _Float16* __restrict__ xlo,
        const float* __restrict__ sq,
        float* __restrict__ candv, int* __restrict__ candi) {
    __shared__ char lds[131072];       // AH|AL|BH|BL x 32KB (one BK=64 chunk); S unions
    __shared__ float topv[256][9];
    __shared__ int   topi[256][9];

    int tid = threadIdx.x, lane = tid & 63, wave = tid >> 6;
    int wr = wave >> 1, wc = wave & 1;
    int l15 = lane & 15, kg = lane >> 4;

    // serpentine column decode: XCD x owns columns {24-x, 9+x, 8-x, (x==7: 0)}
    int xcd = blockIdx.x & 7, idx = blockIdx.x >> 3;
    int p = -1, t = 0;
#pragma unroll
    for (int r = 0; r < 4; r++) {
        int tc = 24 - 8 * r - ((r & 1) ? 7 - xcd : xcd);
        if (tc >= 0 && p < 0) {
            int sz = tc + 1;
            if (idx < sz) { p = idx; t = tc; }
            else idx -= sz;
        }
    }
    if (p < 0) return;                 // dead pad block
    size_t i0 = (size_t)p * 256, j0 = (size_t)t * 256;

    if (tid < 256) {
#pragma unroll
        for (int k = 0; k < 8; k++) { topv[tid][k] = 3.4e38f; topi[tid][k] = 0x7fffffff; }
    }
    __syncthreads();

    f32x4 acc[4][8] = {};

    int srow_in = lane >> 3;                   // 0..7
    int skb = (lane & 7) ^ srow_in;            // pre-swizzled 16B block id

#pragma unroll 1
    for (int c = 0; c < 32; c++) {
        int kk = c * 64;
        // stage 128KB: 128 segs (8 rows x 128B each), 16 per wave
#pragma unroll
        for (int g = 0; g < 16; g++) {
            int sg = wave * 16 + g;
            int tIdx = sg >> 5, seg = sg & 31;
            const _Float16* src = (tIdx & 1) ? xlo : xhi;
            size_t rbase = (tIdx < 2) ? i0 : j0;
            int R = seg * 8;
            gld_lds16(src + (rbase + (size_t)(R + srow_in)) * CDIM + kk + skb * 8,
                      lds + tIdx * 32768 + R * 128);
        }
        __syncthreads();               // drains vmcnt; staging visible to all
        const char* Ah = lds;
        const char* Al = lds + 32768;
        const char* Bh = lds + 65536;
        const char* Bl = lds + 98304;
#pragma unroll
        for (int s = 0; s < 2; s++) {
            half8 ah[4], al[4];
#pragma unroll
            for (int m = 0; m < 4; m++) ah[m] = frag_read(Ah, wr * 64 + m * 16 + l15, s, lane);
#pragma unroll
            for (int m = 0; m < 4; m++) al[m] = frag_read(Al, wr * 64 + m * 16 + l15, s, lane);
#pragma unroll
            for (int n = 0; n < 8; n++) {
                half8 bh = frag_read(Bh, wc * 128 + n * 16 + l15, s, lane);
                half8 bl = frag_read(Bl, wc * 128 + n * 16 + l15, s, lane);
#pragma unroll
                for (int m = 0; m < 4; m++) acc[m][n] = MF(ah[m], bh, acc[m][n]);
#pragma unroll
                for (int m = 0; m < 4; m++) acc[m][n] = MF(al[m], bh, acc[m][n]);
#pragma unroll
                for (int m = 0; m < 4; m++) acc[m][n] = MF(ah[m], bl, acc[m][n]);
            }
        }
        __syncthreads();               // LDS reusable for next chunk
    }

    // sq loads (outside K-loop; guards for the ragged last panel)
    float sqi[4][4];
#pragma unroll
    for (int m = 0; m < 4; m++)
#pragma unroll
        for (int r = 0; r < 4; r++) {
            int gi = (int)i0 + wr * 64 + m * 16 + kg * 4 + r;
            sqi[m][r] = (gi < N_NODES) ? sq[gi] : 0.f;
        }
    float sqj[8];
#pragma unroll
    for (int n = 0; n < 8; n++) {
        int gj = (int)j0 + wc * 128 + n * 16 + l15;
        sqj[n] = (gj < N_NODES) ? sq[gj] : 0.f;
    }

    // ---- row pass: d2 -> S chunks (32 cols), per-row serial top-8 ----
    float* S = (float*)lds;   // [256][33]
#pragma unroll
    for (int cs = 0; cs < 8; cs++) {
        __syncthreads();
        if (wc == (cs >> 2)) {
            const int n0 = (cs & 3) * 2;
#pragma unroll
            for (int m = 0; m < 4; m++)
#pragma unroll
                for (int nn = 0; nn < 2; nn++)
#pragma unroll
                    for (int r = 0; r < 4; r++) {
                        int row = wr * 64 + m * 16 + kg * 4 + r;
                        float d2 = sqi[m][r] + sqj[n0 + nn] - 2.f * acc[m][n0 + nn][r];
                        S[row * 33 + nn * 16 + l15] = d2;
                    }
        }
        __syncthreads();
        if (tid < 256) {
            int r = tid, gi = (int)i0 + r;
            int cbase = (int)j0 + cs * 32;
#pragma unroll 4
            for (int jj = 0; jj < 32; jj++) {
                int gj = cbase + jj;
                if (gj >= N_NODES || gj == gi) continue;
                float v = S[r * 33 + jj];
                float wv = topv[r][7]; int wi = topi[r][7];
                if (v < wv || (v == wv && gj < wi)) {
                    int pos = 7;
                    while (pos > 0) {
                        float pv = topv[r][pos - 1]; int pi = topi[r][pos - 1];
                        if (v < pv || (v == pv && gj < pi)) {
                            topv[r][pos] = pv; topi[r][pos] = pi; pos--;
                        } else break;
                    }
                    topv[r][pos] = v; topi[r][pos] = gj;
                }
            }
        }
    }
    __syncthreads();
    if (tid < 256) {
        int gi = (int)i0 + tid;
        if (gi < N_NODES) {
#pragma unroll
            for (int k = 0; k < 8; k++) {
                candv[(size_t)gi * NSLOT + t * 8 + k] = topv[tid][k];
                candi[(size_t)gi * NSLOT + t * 8 + k] = topi[tid][k];
            }
        }
        // re-init for column pass
#pragma unroll
        for (int k = 0; k < 8; k++) { topv[tid][k] = 3.4e38f; topi[tid][k] = 0x7fffffff; }
    }

    // ---- column pass (off-diagonal tiles only): S^T chunks (32 rows) ----
    if (p < t) {
#pragma unroll
        for (int ss = 0; ss < 8; ss++) {
            __syncthreads();
            if (wr == (ss >> 1)) {
                const int mb = (ss & 1) * 2;
#pragma unroll
                for (int mm = 0; mm < 2; mm++)
#pragma unroll
                    for (int n = 0; n < 8; n++)
#pragma unroll
                        for (int r = 0; r < 4; r++) {
                            int rl  = mm * 16 + kg * 4 + r;          // row_local 0..31
                            int col = wc * 128 + n * 16 + l15;       // 0..255
                            float d2 = sqi[mb + mm][r] + sqj[n] - 2.f * acc[mb + mm][n][r];
                            S[col * 33 + rl] = d2;
                        }
            }
            __syncthreads();
            if (tid < 256) {
                int cc = tid;
                int rbase = (int)i0 + ss * 32;   // candidate rows (p<=23 => valid)
#pragma unroll 4
                for (int jj = 0; jj < 32; jj++) {
                    int gi = rbase + jj;
                    float v = S[cc * 33 + jj];
                    float wv = topv[cc][7]; int wi = topi[cc][7];
                    if (v < wv || (v == wv && gi < wi)) {
                        int pos = 7;
                        while (pos > 0) {
                            float pv = topv[cc][pos - 1]; int pi = topi[cc][pos - 1];
                            if (v < pv || (v == pv && gi < pi)) {
                                topv[cc][pos] = pv; topi[cc][pos] = pi; pos--;
                            } else break;
                        }
                        topv[cc][pos] = v; topi[cc][pos] = gi;
                    }
                }
            }
        }
        __syncthreads();
        if (tid < 256) {
            int gj = (int)j0 + tid;
            if (gj < N_NODES) {
#pragma unroll
                for (int k = 0; k < 8; k++) {
                    candv[(size_t)gj * NSLOT + p * 8 + k] = topv[tid][k];
                    candi[(size_t)gj * NSLOT + p * 8 + k] = topi[tid][k];
                }
            }
        }
    }
}

// ------------- merge 25 sorted 8-lists -> knn (wave per node, lex (v,idx)) -----
__global__ __launch_bounds__(256) void merge_topk_kernel(
        const float* __restrict__ candv, const int* __restrict__ candi,
        int* __restrict__ knn) {
    int node = blockIdx.x * 4 + (threadIdx.x >> 6);
    int lane = threadIdx.x & 63;
    const float* cv = candv + (size_t)node * NSLOT;
    const int*   ci = candi + (size_t)node * NSLOT;
    float v[4]; int ix[4];
#pragma unroll
    for (int u = 0; u < 4; u++) {
        int s = u * 64 + lane;
        bool ok = (s < NSLOT);
        v[u]  = ok ? cv[s] : 3.4e38f;
        ix[u] = ok ? ci[s] : 0x7fffffff;
    }
#pragma unroll 1
    for (int k = 0; k < 8; k++) {
        float bv = v[0]; int bi = ix[0];
#pragma unroll
        for (int u = 1; u < 4; u++)
            if (v[u] < bv || (v[u] == bv && ix[u] < bi)) { bv = v[u]; bi = ix[u]; }
#pragma unroll
        for (int off = 32; off; off >>= 1) {
            float ov = __shfl_xor(bv, off, 64);
            int   oi = __shfl_xor(bi, off, 64);
            if (ov < bv || (ov == bv && oi < bi)) { bv = ov; bi = oi; }
        }
        if (lane == 0) knn[(size_t)node * 8 + k] = bi;
#pragma unroll
        for (int u = 0; u < 4; u++)
            if (ix[u] == bi) { v[u] = 3.4e38f; ix[u] = 0x7fffffff; }
    }
}

// ------------- graph build -------------
__global__ __launch_bounds__(256) void graph_init_kernel(int* deg, int* cnt) {
    int i = blockIdx.x * 256 + threadIdx.x;
    if (i < N_NODES) { deg[i] = 1; cnt[i] = 0; }
}
__global__ __launch_bounds__(256) void deg_count_kernel(const int* __restrict__ knn,
                                                        int* deg) {
    int e = blockIdx.x * 256 + threadIdx.x;
    if (e < N_NODES * 8) atomicAdd(&deg[knn[e]], 1);
}
__global__ __launch_bounds__(256) void dinv_kernel(const int* __restrict__ deg,
                                                   float* __restrict__ dinv) {
    int i = blockIdx.x * 256 + threadIdx.x;
    if (i < N_NODES) dinv[i] = rsqrtf((float)deg[i]);
}
__global__ __launch_bounds__(256) void scan_kernel(const int* __restrict__ deg,
                                                   int* __restrict__ row_ptr) {
    __shared__ int partial[256];
    const int CHUNK = (N_NODES + 255) / 256;
    int tid = threadIdx.x;
    int start = tid * CHUNK;
    int end = start + CHUNK; if (end > N_NODES) end = N_NODES;
    int s = 0;
    for (int i = start; i < end; i++) s += deg[i];
    partial[tid] = s;
    __syncthreads();
    if (tid == 0) {
        int run = 0;
        for (int k = 0; k < 256; k++) { int v = partial[k]; partial[k] = run; run += v; }
        row_ptr[N_NODES] = run;
    }
    __syncthreads();
    int run = partial[tid];
    for (int i = start; i < end; i++) { row_ptr[i] = run; run += deg[i]; }
}
__global__ __launch_bounds__(256) void scatter_kernel(const int* __restrict__ knn,
        const int* __restrict__ row_ptr, int* cnt, int* __restrict__ col) {
    int i = blockIdx.x * 256 + threadIdx.x;
    if (i >= N_NODES) return;
    int ptr = row_ptr[i] + atomicAdd(&cnt[i], 1);
    col[ptr] = i;                                   // self-loop
#pragma unroll
    for (int j = 0; j < 8; j++) {
        int d = knn[(size_t)i * 8 + j];
        int q = row_ptr[d] + atomicAdd(&cnt[d], 1);
        col[q] = i;
    }
}

// ------------- fp16 MFMA GEMM  C[M,N] = A[M,K] @ Bt[N,K]^T  (f32 out) --------
__global__ __launch_bounds__(256) void hgemm_nt_kernel(
        const _Float16* __restrict__ A, const _Float16* __restrict__ Bt,
        float* __restrict__ C, int M, int N, int K) {
    __shared__ char Alds[16384], Blds[16384];
    int tid = threadIdx.x, lane = tid & 63, wave = tid >> 6;
    int wr = wave >> 1, wc = wave & 1;
    int l15 = lane & 15, kg = lane >> 4;
    int nt = N >> 7;
    int i0 = (blockIdx.x / nt) * 128, j0 = (blockIdx.x % nt) * 128;
    f32x4 acc[4][4] = {};

#pragma unroll 1
    for (int kk = 0; kk < K; kk += 64) {
        __syncthreads();
#pragma unroll
        for (int g = 0; g < 4; g++) {
            int R = wave * 32 + g * 8;
            int swzk = ((lane & 7) ^ (lane >> 3)) << 3;
            const _Float16* ga = A + (size_t)(i0 + R + (lane >> 3)) * K + kk + swzk;
            gld_lds16(ga, Alds + R * 128);
            const _Float16* gb = Bt + (size_t)(j0 + R + (lane >> 3)) * K + kk + swzk;
            gld_lds16(gb, Blds + R * 128);
        }
        __syncthreads();
#pragma unroll
        for (int s = 0; s < 2; s++) {
            half8 a[4], b[4];
#pragma unroll
            for (int m = 0; m < 4; m++) a[m] = frag_read(Alds, wr * 64 + m * 16 + l15, s, lane);
#pragma unroll
            for (int n = 0; n < 4; n++) b[n] = frag_read(Blds, wc * 64 + n * 16 + l15, s, lane);
#pragma unroll
            for (int m = 0; m < 4; m++)
#pragma unroll
                for (int n = 0; n < 4; n++)
                    acc[m][n] = __builtin_amdgcn_mfma_f32_16x16x32_f16(a[m], b[n], acc[m][n], 0, 0, 0);
        }
    }
#pragma unroll
    for (int m = 0; m < 4; m++)
#pragma unroll
        for (int n = 0; n < 4; n++)
#pragma unroll
            for (int r = 0; r < 4; r++) {
                int row = i0 + wr * 64 + m * 16 + kg * 4 + r;
                int colj = j0 + wc * 64 + n * 16 + l15;
                C[(size_t)row * N + colj] = acc[m][n][r];
            }
}

// ------------- GCN aggregation: out[d] = relu(dinv[d]*sum hw[s]*dinv[s] + b) ---
template <bool HALF>
__global__ __launch_bounds__(256) void aggregate_kernel(
        const float* __restrict__ hw, const int* __restrict__ row_ptr,
        const int* __restrict__ col, const float* __restrict__ dinv,
        const float* __restrict__ bias, void* __restrict__ outp) {
    int node = blockIdx.x * 4 + (threadIdx.x >> 6);
    int lane = threadIdx.x & 63;
    int e0 = row_ptr[node], e1 = row_ptr[node + 1];
    float4 acc0 = {0.f, 0.f, 0.f, 0.f}, acc1 = {0.f, 0.f, 0.f, 0.f};
    for (int e = e0; e < e1; e++) {
        int s = col[e];
        float w = dinv[s];
        const float* hr = hw + (size_t)s * ODIM;
        float4 v0 = *(const float4*)(hr + lane * 4);
        float4 v1 = *(const float4*)(hr + 256 + lane * 4);
        acc0.x = fmaf(w, v0.x, acc0.x); acc0.y = fmaf(w, v0.y, acc0.y);
        acc0.z = fmaf(w, v0.z, acc0.z); acc0.w = fmaf(w, v0.w, acc0.w);
        acc1.x = fmaf(w, v1.x, acc1.x); acc1.y = fmaf(w, v1.y, acc1.y);
        acc1.z = fmaf(w, v1.z, acc1.z); acc1.w = fmaf(w, v1.w, acc1.w);
    }
    float wd = dinv[node];
    float4 b0 = *(const float4*)(bias + lane * 4);
    float4 b1 = *(const float4*)(bias + 256 + lane * 4);
    float o[8];
    o[0] = fmaxf(fmaf(acc0.x, wd, b0.x), 0.f);
    o[1] = fmaxf(fmaf(acc0.y, wd, b0.y), 0.f);
    o[2] = fmaxf(fmaf(acc0.z, wd, b0.z), 0.f);
    o[3] = fmaxf(fmaf(acc0.w, wd, b0.w), 0.f);
    o[4] = fmaxf(fmaf(acc1.x, wd, b1.x), 0.f);
    o[5] = fmaxf(fmaf(acc1.y, wd, b1.y), 0.f);
    o[6] = fmaxf(fmaf(acc1.z, wd, b1.z), 0.f);
    o[7] = fmaxf(fmaf(acc1.w, wd, b1.w), 0.f);
    if (HALF) {
        _Float16* out = (_Float16*)outp;
        half4 h0, h1;
#pragma unroll
        for (int j = 0; j < 4; j++) { h0[j] = (_Float16)o[j]; h1[j] = (_Float16)o[4 + j]; }
        *(half4*)(out + (size_t)node * ODIM + lane * 4)       = h0;
        *(half4*)(out + (size_t)node * ODIM + 256 + lane * 4) = h1;
    } else {
        float* out = (float*)outp;
        float4 f0 = {o[0], o[1], o[2], o[3]}, f1 = {o[4], o[5], o[6], o[7]};
        *(float4*)(out + (size_t)node * ODIM + lane * 4)       = f0;
        *(float4*)(out + (size_t)node * ODIM + 256 + lane * 4) = f1;
    }
}

extern "C" void kernel_launch(void* const* d_in, const int* in_sizes, int n_in,
                              void* d_out, int out_size, void* d_ws, size_t ws_size,
                              hipStream_t stream) {
    const float* x  = (const float*)d_in[0];
    const float* W1 = (const float*)d_in[1];
    const float* b1 = (const float*)d_in[2];
    const float* W2 = (const float*)d_in[3];
    const float* b2 = (const float*)d_in[4];
    float* out = (float*)d_out;
    char* ws = (char*)d_ws;

    _Float16* xhi  = (_Float16*)(ws + XHI_OFF);
    _Float16* xlo  = (_Float16*)(ws + XLO_OFF);
    float* candv   = (float*)(ws + CANDV_OFF);
    int*   candi   = (int*)  (ws + CANDI_OFF);
    float* sq      = (float*)(ws + SQ_OFF);
    int*   knn     = (int*)  (ws + KNN_OFF);
    int*   deg     = (int*)  (ws + DEG_OFF);
    int*   cnt     = (int*)  (ws + CNT_OFF);
    float* dinv    = (float*)(ws + DINV_OFF);
    int*   row_ptr = (int*)  (ws + RPTR_OFF);
    int*   col     = (int*)  (ws + COL_OFF);
    _Float16* w1t  = (_Float16*)(ws + W1T_OFF);
    _Float16* w2t  = (_Float16*)(ws + W2T_OFF);
    float* hw      = (float*)(ws + HW_OFF);       // reuses xlo region (post-gram)
    _Float16* h1h  = (_Float16*)(ws + H1H_OFF);   // reuses xlo region (post-gram)

    conv_split_kernel<<<12544, 256, 0, stream>>>(x, xhi, xlo);
    sq_kernel<<<N_NODES, 64, 0, stream>>>(x, sq);
    wtrans_kernel<<<dim3(CDIM / 64, ODIM / 64), 256, 0, stream>>>(W1, w1t, CDIM, ODIM);
    wtrans_kernel<<<dim3(ODIM / 64, ODIM / 64), 256, 0, stream>>>(W2, w2t, ODIM, ODIM);

    gram_topk_mfma<<<GRID_G, 512, 0, stream>>>(xhi, xlo, sq, candv, candi);
    merge_topk_kernel<<<N_NODES / 4, 256, 0, stream>>>(candv, candi, knn);

    graph_init_kernel<<<(N_NODES + 255) / 256, 256, 0, stream>>>(deg, cnt);
    deg_count_kernel<<<(N_NODES * 8) / 256, 256, 0, stream>>>(knn, deg);
    dinv_kernel<<<(N_NODES + 255) / 256, 256, 0, stream>>>(deg, dinv);
    scan_kernel<<<1, 256, 0, stream>>>(deg, row_ptr);
    scatter_kernel<<<(N_NODES + 255) / 256, 256, 0, stream>>>(knn, row_ptr, cnt, col);

    hgemm_nt_kernel<<<(N_NODES / 128) * (ODIM / 128), 256, 0, stream>>>(xhi, w1t, hw, N_NODES, ODIM, CDIM);
    aggregate_kernel<true><<<N_NODES / 4, 256, 0, stream>>>(hw, row_ptr, col, dinv, b1, (void*)h1h);
    hgemm_nt_kernel<<<(N_NODES / 128) * (ODIM / 128), 256, 0, stream>>>(h1h, w2t, hw, N_NODES, ODIM, ODIM);
    aggregate_kernel<false><<<N_NODES / 4, 256, 0, stream>>>(hw, row_ptr, col, dinv, b2, (void*)out);
}

// Round 11
// 1354.503 us; speedup vs baseline: 1.6644x; 1.2782x over previous
//
#include <hip/hip_runtime.h>

typedef __attribute__((ext_vector_type(8))) _Float16 half8;
typedef __attribute__((ext_vector_type(4))) _Float16 half4;
typedef __attribute__((ext_vector_type(4))) float f32x4;

#define N_NODES 6272
#define CDIM    2048
#define ODIM    512
#define NPAN    49       // 6272 / 128 node panels
#define NSLOT   392      // 49 panels * 8 candidates per node
#define GRID_G  1232     // 8 x 154 (1225 live triangle tiles + 7 dead)

// ---------------- workspace layout (bytes) ----------------
#define XHI_OFF    0ul
#define XLO_OFF    25690112ul
#define CANDV_OFF  51380224ul          // 6272*392*4  = 9,834,496
#define CANDI_OFF  61214720ul          // 6272*392*2  = 4,917,248 (u16)
#define SQ_OFF     66131968ul
#define KNN_OFF    66157056ul
#define DEG_OFF    66357760ul
#define CNT_OFF    66382848ul
#define DINV_OFF   66407936ul
#define RPTR_OFF   66433024ul
#define COL_OFF    66458368ul
#define W1T_OFF    66684160ul
#define W2T_OFF    68781312ul          // end 69,305,600
// hw (f32, 12.8MB) and h1h (fp16, 6.4MB) reuse the XLO region after gram is done
#define HW_OFF     XLO_OFF
#define H1H_OFF    (XLO_OFF + 12845056ul)

// ---------------- async global->LDS (16B per lane, wave-uniform LDS base) ----
__device__ __forceinline__ void gld_lds16(const void* g, void* l) {
    __builtin_amdgcn_global_load_lds(
        (const __attribute__((address_space(1))) void*)g,
        (__attribute__((address_space(3))) void*)l, 16, 0, 0);
}

// BK=64 tile (hgemm): [row][128B]; 16B slot b holds global k-block b ^ (row&7).
__device__ __forceinline__ half8 frag_read(const char* base, int row, int s, int lane) {
    int b = (s * 4 + (lane >> 4)) ^ (row & 7);
    return *(const half8*)(base + row * 128 + b * 16);
}

#define MF(a, b, c) __builtin_amdgcn_mfma_f32_16x16x32_f16(a, b, c, 0, 0, 0)

// ---------------- x -> (hi, lo) fp16 split ----------------
__global__ __launch_bounds__(256) void conv_split_kernel(const float* __restrict__ x,
        _Float16* __restrict__ xhi, _Float16* __restrict__ xlo) {
    size_t idx = ((size_t)blockIdx.x * 256 + threadIdx.x) * 4;
    float4 v = *(const float4*)(x + idx);
    float vv[4] = {v.x, v.y, v.z, v.w};
    half4 h, l;
#pragma unroll
    for (int j = 0; j < 4; j++) {
        _Float16 hj = (_Float16)vv[j];
        h[j] = hj;
        l[j] = (_Float16)(vv[j] - (float)hj);
    }
    *(half4*)(xhi + idx) = h;
    *(half4*)(xlo + idx) = l;
}

// ---------------- W [K][N] f32 -> Wt [N][K] f16 ----------------
__global__ __launch_bounds__(256) void wtrans_kernel(const float* __restrict__ W,
        _Float16* __restrict__ Wt, int K, int N) {
    __shared__ float tile[64][65];
    int kb = blockIdx.x * 64, nb = blockIdx.y * 64;
    int tid = threadIdx.x;
    int r = tid >> 2, c0 = (tid & 3) * 16;
#pragma unroll
    for (int u = 0; u < 4; u++) {
        float4 v = *(const float4*)(W + (size_t)(kb + r) * N + nb + c0 + u * 4);
        tile[r][c0 + u * 4 + 0] = v.x; tile[r][c0 + u * 4 + 1] = v.y;
        tile[r][c0 + u * 4 + 2] = v.z; tile[r][c0 + u * 4 + 3] = v.w;
    }
    __syncthreads();
    int rn = tid >> 2, ck0 = (tid & 3) * 16;
#pragma unroll
    for (int u = 0; u < 4; u++) {
        half4 o;
#pragma unroll
        for (int j = 0; j < 4; j++) o[j] = (_Float16)tile[ck0 + u * 4 + j][rn];
        *(half4*)(Wt + (size_t)(nb + rn) * K + kb + ck0 + u * 4) = o;
    }
}

// ---------------- sq[i] = sum_c x[i][c]^2 (fp32, exact vs ref) ----------------
__global__ __launch_bounds__(64) void sq_kernel(const float* __restrict__ x,
                                                float* __restrict__ sq) {
    int i = blockIdx.x;
    int t = threadIdx.x;
    const float* row = x + (size_t)i * CDIM;
    float s = 0.f;
#pragma unroll
    for (int k = 0; k < CDIM / 256; k++) {
        float4 v = *(const float4*)(row + (k * 64 + t) * 4);
        s += v.x * v.x + v.y * v.y + v.z * v.z + v.w * v.w;
    }
#pragma unroll
    for (int off = 32; off; off >>= 1) s += __shfl_down(s, off, 64);
    if (t == 0) sq[i] = s;
}

// ---- fused MFMA Gram: upper-tri 128x128 tiles, 4 blocks/CU, row+col top-8 ----
// dot = hi.hi + hi.lo + lo.hi. m97-regime replica: 256 threads (4 waves),
// 32 KB LDS per block -> 4 co-resident blocks/CU (the m102-verified residency
// that sustains 23 B/cy/CU staging), simple stage->sync->MFMA->sync loop.
// LDS layout: A|B tiles of [128 rows][128B]; 16B slot b of row holds logical
// (kg,hilo) = b ^ (row&7): hi/lo INTERLEAVED, staged from two arrays via
// per-lane base select in one gld_lds16 stream. Epilogue S + top-lists overlay
// the staging buffer. All acc[][] indices compile-time (rule #20).
__global__ __launch_bounds__(256, 4) void gram_topk_mfma(
        const _Float16* __restrict__ xhi, const _Float16* __restrict__ xlo,
        const float* __restrict__ sq,
        float* __restrict__ candv, unsigned short* __restrict__ candi) {
    __shared__ char lds[32768];
    float* S = (float*)lds;                                  // [128][33] 16.9KB
    float* topv = (float*)(lds + 16896);                     // [128][9]  4.6KB
    unsigned short* topi = (unsigned short*)(lds + 21504);   // [128][10] 2.6KB
#define TOPV(r, k) topv[(r) * 9 + (k)]
#define TOPI(r, k) topi[(r) * 10 + (k)]

    int tid = threadIdx.x, lane = tid & 63, wave = tid >> 6;   // 4 waves
    int wr = wave >> 1, wc = wave & 1;
    int l15 = lane & 15, kg = lane >> 4;

    // bijective XCD chunking over t-major triangle raster (1225 = 8*153 + 1)
    int xcd = blockIdx.x & 7, loc = blockIdx.x >> 3;
    if (xcd != 0 && loc >= 153) return;                        // dead pads
    int raster = (xcd == 0) ? loc : (154 + (xcd - 1) * 153 + loc);
    int t = (int)((sqrtf(8.f * (float)raster + 1.f) - 1.f) * 0.5f);
    while ((t + 1) * (t + 2) / 2 <= raster) t++;
    while (t * (t + 1) / 2 > raster) t--;
    int p = raster - t * (t + 1) / 2;                          // p <= t
    size_t i0 = (size_t)p * 128, j0 = (size_t)t * 128;

    f32x4 acc[4][4] = {};

    // staging lane constants: slot (row r_in, block lane&7) holds logical
    // kg2h = (lane&7)^r_in; hilo selects source array, kg the k-subblock.
    int r_in = lane >> 3;
    int kg2h = (lane & 7) ^ r_in;
    const _Float16* sbase = (kg2h & 1) ? xlo : xhi;
    int koff = (kg2h >> 1) * 8;

#pragma unroll 1
    for (int c = 0; c < 64; c++) {
        int kbase = c * 32 + koff;
#pragma unroll
        for (int g = 0; g < 8; g++) {          // 32 segs (8 rows x 128B), 8/wave
            int sg = wave * 8 + g;
            int tI = sg >> 4, seg = sg & 15;
            size_t row = (tI ? j0 : i0) + (size_t)(seg * 8 + r_in);
            gld_lds16(sbase + row * CDIM + kbase, lds + tI * 16384 + seg * 1024);
        }
        __syncthreads();
        const char* At = lds;
        const char* Bt = lds + 16384;
        half8 ah[4], al[4];
#pragma unroll
        for (int m = 0; m < 4; m++) {
            int row = wr * 64 + m * 16 + l15;
            ah[m] = *(const half8*)(At + row * 128 + ((((kg << 1) | 0) ^ (row & 7)) << 4));
            al[m] = *(const half8*)(At + row * 128 + ((((kg << 1) | 1) ^ (row & 7)) << 4));
        }
#pragma unroll
        for (int n = 0; n < 4; n++) {
            int row = wc * 64 + n * 16 + l15;
            half8 bh = *(const half8*)(Bt + row * 128 + ((((kg << 1) | 0) ^ (row & 7)) << 4));
            half8 bl = *(const half8*)(Bt + row * 128 + ((((kg << 1) | 1) ^ (row & 7)) << 4));
#pragma unroll
            for (int m = 0; m < 4; m++) acc[m][n] = MF(ah[m], bh, acc[m][n]);
#pragma unroll
            for (int m = 0; m < 4; m++) acc[m][n] = MF(al[m], bh, acc[m][n]);
#pragma unroll
            for (int m = 0; m < 4; m++) acc[m][n] = MF(ah[m], bl, acc[m][n]);
        }
        __syncthreads();
    }

    // sq values (6272 = 49*128: no guards needed)
    float sqi[4][4];
#pragma unroll
    for (int m = 0; m < 4; m++)
#pragma unroll
        for (int r = 0; r < 4; r++)
            sqi[m][r] = sq[(int)i0 + wr * 64 + m * 16 + kg * 4 + r];
    float sqj[4];
#pragma unroll
    for (int n = 0; n < 4; n++)
        sqj[n] = sq[(int)j0 + wc * 64 + n * 16 + l15];

    // init top lists (staging LDS now free; lists live beside S)
    if (tid < 128) {
#pragma unroll
        for (int k = 0; k < 8; k++) { TOPV(tid, k) = 3.4e38f; TOPI(tid, k) = 0xFFFF; }
    }

    // ---- row pass: 4 chunks of 32 cols ----
#pragma unroll
    for (int cs = 0; cs < 4; cs++) {
        __syncthreads();
        if (wc == (cs >> 1)) {
            const int n0 = (cs & 1) * 2;
#pragma unroll
            for (int m = 0; m < 4; m++)
#pragma unroll
                for (int nn = 0; nn < 2; nn++)
#pragma unroll
                    for (int r = 0; r < 4; r++) {
                        int row = wr * 64 + m * 16 + kg * 4 + r;
                        float d2 = sqi[m][r] + sqj[n0 + nn] - 2.f * acc[m][n0 + nn][r];
                        S[row * 33 + nn * 16 + l15] = d2;
                    }
        }
        __syncthreads();
        if (tid < 128) {
            int r = tid, gi = (int)i0 + r;
            int cbase = (int)j0 + cs * 32;
#pragma unroll 4
            for (int jj = 0; jj < 32; jj++) {
                int gj = cbase + jj;
                if (gj == gi) continue;
                float v = S[r * 33 + jj];
                float wv = TOPV(r, 7); int wi = TOPI(r, 7);
                if (v < wv || (v == wv && gj < wi)) {
                    int pos = 7;
                    while (pos > 0) {
                        float pv = TOPV(r, pos - 1); int pi = TOPI(r, pos - 1);
                        if (v < pv || (v == pv && gj < pi)) {
                            TOPV(r, pos) = pv; TOPI(r, pos) = (unsigned short)pi; pos--;
                        } else break;
                    }
                    TOPV(r, pos) = v; TOPI(r, pos) = (unsigned short)gj;
                }
            }
        }
    }
    __syncthreads();
    if (tid < 128) {
        int gi = (int)i0 + tid;
#pragma unroll
        for (int k = 0; k < 8; k++) {
            candv[(size_t)gi * NSLOT + t * 8 + k] = TOPV(tid, k);
            candi[(size_t)gi * NSLOT + t * 8 + k] = TOPI(tid, k);
        }
        // re-init for column pass
#pragma unroll
        for (int k = 0; k < 8; k++) { TOPV(tid, k) = 3.4e38f; TOPI(tid, k) = 0xFFFF; }
    }

    // ---- column pass (off-diagonal only): 4 chunks of 32 rows ----
    if (p < t) {
#pragma unroll
        for (int ss = 0; ss < 4; ss++) {
            __syncthreads();
            if (wr == (ss >> 1)) {
                const int mb = (ss & 1) * 2;
#pragma unroll
                for (int mm = 0; mm < 2; mm++)
#pragma unroll
                    for (int n = 0; n < 4; n++)
#pragma unroll
                        for (int r = 0; r < 4; r++) {
                            int rl  = mm * 16 + kg * 4 + r;
                            int col = wc * 64 + n * 16 + l15;
                            float d2 = sqi[mb + mm][r] + sqj[n] - 2.f * acc[mb + mm][n][r];
                            S[col * 33 + rl] = d2;
                        }
            }
            __syncthreads();
            if (tid < 128) {
                int cc = tid;
                int rbase = (int)i0 + ss * 32;
#pragma unroll 4
                for (int jj = 0; jj < 32; jj++) {
                    int gi = rbase + jj;
                    float v = S[cc * 33 + jj];
                    float wv = TOPV(cc, 7); int wi = TOPI(cc, 7);
                    if (v < wv || (v == wv && gi < wi)) {
                        int pos = 7;
                        while (pos > 0) {
                            float pv = TOPV(cc, pos - 1); int pi = TOPI(cc, pos - 1);
                            if (v < pv || (v == pv && gi < pi)) {
                                TOPV(cc, pos) = pv; TOPI(cc, pos) = (unsigned short)pi; pos--;
                            } else break;
                        }
                        TOPV(cc, pos) = v; TOPI(cc, pos) = (unsigned short)gi;
                    }
                }
            }
        }
        __syncthreads();
        if (tid < 128) {
            int gj = (int)j0 + tid;
#pragma unroll
            for (int k = 0; k < 8; k++) {
                candv[(size_t)gj * NSLOT + p * 8 + k] = TOPV(tid, k);
                candi[(size_t)gj * NSLOT + p * 8 + k] = TOPI(tid, k);
            }
        }
    }
#undef TOPV
#undef TOPI
}

// ------------- merge 49 sorted 8-lists -> knn (wave per node, lex (v,idx)) -----
__global__ __launch_bounds__(256) void merge_topk_kernel(
        const float* __restrict__ candv, const unsigned short* __restrict__ candi,
        int* __restrict__ knn) {
    int node = blockIdx.x * 4 + (threadIdx.x >> 6);
    int lane = threadIdx.x & 63;
    const float* cv = candv + (size_t)node * NSLOT;
    const unsigned short* ci = candi + (size_t)node * NSLOT;
    float v[7]; int ix[7];
#pragma unroll
    for (int u = 0; u < 7; u++) {
        int s = u * 64 + lane;
        bool ok = (s < NSLOT);
        v[u]  = ok ? cv[s] : 3.4e38f;
        ix[u] = ok ? (int)ci[s] : 0x7fffffff;
    }
#pragma unroll 1
    for (int k = 0; k < 8; k++) {
        float bv = v[0]; int bi = ix[0];
#pragma unroll
        for (int u = 1; u < 7; u++)
            if (v[u] < bv || (v[u] == bv && ix[u] < bi)) { bv = v[u]; bi = ix[u]; }
#pragma unroll
        for (int off = 32; off; off >>= 1) {
            float ov = __shfl_xor(bv, off, 64);
            int   oi = __shfl_xor(bi, off, 64);
            if (ov < bv || (ov == bv && oi < bi)) { bv = ov; bi = oi; }
        }
        if (lane == 0) knn[(size_t)node * 8 + k] = bi;
#pragma unroll
        for (int u = 0; u < 7; u++)
            if (ix[u] == bi) { v[u] = 3.4e38f; ix[u] = 0x7fffffff; }
    }
}

// ------------- graph build -------------
__global__ __launch_bounds__(256) void graph_init_kernel(int* deg, int* cnt) {
    int i = blockIdx.x * 256 + threadIdx.x;
    if (i < N_NODES) { deg[i] = 1; cnt[i] = 0; }
}
__global__ __launch_bounds__(256) void deg_count_kernel(const int* __restrict__ knn,
                                                        int* deg) {
    int e = blockIdx.x * 256 + threadIdx.x;
    if (e < N_NODES * 8) atomicAdd(&deg[knn[e]], 1);
}
__global__ __launch_bounds__(256) void dinv_kernel(const int* __restrict__ deg,
                                                   float* __restrict__ dinv) {
    int i = blockIdx.x * 256 + threadIdx.x;
    if (i < N_NODES) dinv[i] = rsqrtf((float)deg[i]);
}
__global__ __launch_bounds__(256) void scan_kernel(const int* __restrict__ deg,
                                                   int* __restrict__ row_ptr) {
    __shared__ int partial[256];
    const int CHUNK = (N_NODES + 255) / 256;
    int tid = threadIdx.x;
    int start = tid * CHUNK;
    int end = start + CHUNK; if (end > N_NODES) end = N_NODES;
    int s = 0;
    for (int i = start; i < end; i++) s += deg[i];
    partial[tid] = s;
    __syncthreads();
    if (tid == 0) {
        int run = 0;
        for (int k = 0; k < 256; k++) { int v = partial[k]; partial[k] = run; run += v; }
        row_ptr[N_NODES] = run;
    }
    __syncthreads();
    int run = partial[tid];
    for (int i = start; i < end; i++) { row_ptr[i] = run; run += deg[i]; }
}
__global__ __launch_bounds__(256) void scatter_kernel(const int* __restrict__ knn,
        const int* __restrict__ row_ptr, int* cnt, int* __restrict__ col) {
    int i = blockIdx.x * 256 + threadIdx.x;
    if (i >= N_NODES) return;
    int ptr = row_ptr[i] + atomicAdd(&cnt[i], 1);
    col[ptr] = i;                                   // self-loop
#pragma unroll
    for (int j = 0; j < 8; j++) {
        int d = knn[(size_t)i * 8 + j];
        int q = row_ptr[d] + atomicAdd(&cnt[d], 1);
        col[q] = i;
    }
}

// ------------- fp16 MFMA GEMM  C[M,N] = A[M,K] @ Bt[N,K]^T  (f32 out) --------
__global__ __launch_bounds__(256) void hgemm_nt_kernel(
        const _Float16* __restrict__ A, const _Float16* __restrict__ Bt,
        float* __restrict__ C, int M, int N, int K) {
    __shared__ char Alds[16384], Blds[16384];
    int tid = threadIdx.x, lane = tid & 63, wave = tid >> 6;
    int wr = wave >> 1, wc = wave & 1;
    int l15 = lane & 15, kg = lane >> 4;
    int nt = N >> 7;
    int i0 = (blockIdx.x / nt) * 128, j0 = (blockIdx.x % nt) * 128;
    f32x4 acc[4][4] = {};

#pragma unroll 1
    for (int kk = 0; kk < K; kk += 64) {
        __syncthreads();
#pragma unroll
        for (int g = 0; g < 4; g++) {
            int R = wave * 32 + g * 8;
            int swzk = ((lane & 7) ^ (lane >> 3)) << 3;
            const _Float16* ga = A + (size_t)(i0 + R + (lane >> 3)) * K + kk + swzk;
            gld_lds16(ga, Alds + R * 128);
            const _Float16* gb = Bt + (size_t)(j0 + R + (lane >> 3)) * K + kk + swzk;
            gld_lds16(gb, Blds + R * 128);
        }
        __syncthreads();
#pragma unroll
        for (int s = 0; s < 2; s++) {
            half8 a[4], b[4];
#pragma unroll
            for (int m = 0; m < 4; m++) a[m] = frag_read(Alds, wr * 64 + m * 16 + l15, s, lane);
#pragma unroll
            for (int n = 0; n < 4; n++) b[n] = frag_read(Blds, wc * 64 + n * 16 + l15, s, lane);
#pragma unroll
            for (int m = 0; m < 4; m++)
#pragma unroll
                for (int n = 0; n < 4; n++)
                    acc[m][n] = __builtin_amdgcn_mfma_f32_16x16x32_f16(a[m], b[n], acc[m][n], 0, 0, 0);
        }
    }
#pragma unroll
    for (int m = 0; m < 4; m++)
#pragma unroll
        for (int n = 0; n < 4; n++)
#pragma unroll
            for (int r = 0; r < 4; r++) {
                int row = i0 + wr * 64 + m * 16 + kg * 4 + r;
                int colj = j0 + wc * 64 + n * 16 + l15;
                C[(size_t)row * N + colj] = acc[m][n][r];
            }
}

// ------------- GCN aggregation: out[d] = relu(dinv[d]*sum hw[s]*dinv[s] + b) ---
template <bool HALF>
__global__ __launch_bounds__(256) void aggregate_kernel(
        const float* __restrict__ hw, const int* __restrict__ row_ptr,
        const int* __restrict__ col, const float* __restrict__ dinv,
        const float* __restrict__ bias, void* __restrict__ outp) {
    int node = blockIdx.x * 4 + (threadIdx.x >> 6);
    int lane = threadIdx.x & 63;
    int e0 = row_ptr[node], e1 = row_ptr[node + 1];
    float4 acc0 = {0.f, 0.f, 0.f, 0.f}, acc1 = {0.f, 0.f, 0.f, 0.f};
    for (int e = e0; e < e1; e++) {
        int s = col[e];
        float w = dinv[s];
        const float* hr = hw + (size_t)s * ODIM;
        float4 v0 = *(const float4*)(hr + lane * 4);
        float4 v1 = *(const float4*)(hr + 256 + lane * 4);
        acc0.x = fmaf(w, v0.x, acc0.x); acc0.y = fmaf(w, v0.y, acc0.y);
        acc0.z = fmaf(w, v0.z, acc0.z); acc0.w = fmaf(w, v0.w, acc0.w);
        acc1.x = fmaf(w, v1.x, acc1.x); acc1.y = fmaf(w, v1.y, acc1.y);
        acc1.z = fmaf(w, v1.z, acc1.z); acc1.w = fmaf(w, v1.w, acc1.w);
    }
    float wd = dinv[node];
    float4 b0 = *(const float4*)(bias + lane * 4);
    float4 b1 = *(const float4*)(bias + 256 + lane * 4);
    float o[8];
    o[0] = fmaxf(fmaf(acc0.x, wd, b0.x), 0.f);
    o[1] = fmaxf(fmaf(acc0.y, wd, b0.y), 0.f);
    o[2] = fmaxf(fmaf(acc0.z, wd, b0.z), 0.f);
    o[3] = fmaxf(fmaf(acc0.w, wd, b0.w), 0.f);
    o[4] = fmaxf(fmaf(acc1.x, wd, b1.x), 0.f);
    o[5] = fmaxf(fmaf(acc1.y, wd, b1.y), 0.f);
    o[6] = fmaxf(fmaf(acc1.z, wd, b1.z), 0.f);
    o[7] = fmaxf(fmaf(acc1.w, wd, b1.w), 0.f);
    if (HALF) {
        _Float16* out = (_Float16*)outp;
        half4 h0, h1;
#pragma unroll
        for (int j = 0; j < 4; j++) { h0[j] = (_Float16)o[j]; h1[j] = (_Float16)o[4 + j]; }
        *(half4*)(out + (size_t)node * ODIM + lane * 4)       = h0;
        *(half4*)(out + (size_t)node * ODIM + 256 + lane * 4) = h1;
    } else {
        float* out = (float*)outp;
        float4 f0 = {o[0], o[1], o[2], o[3]}, f1 = {o[4], o[5], o[6], o[7]};
        *(float4*)(out + (size_t)node * ODIM + lane * 4)       = f0;
        *(float4*)(out + (size_t)node * ODIM + 256 + lane * 4) = f1;
    }
}

extern "C" void kernel_launch(void* const* d_in, const int* in_sizes, int n_in,
                              void* d_out, int out_size, void* d_ws, size_t ws_size,
                              hipStream_t stream) {
    const float* x  = (const float*)d_in[0];
    const float* W1 = (const float*)d_in[1];
    const float* b1 = (const float*)d_in[2];
    const float* W2 = (const float*)d_in[3];
    const float* b2 = (const float*)d_in[4];
    float* out = (float*)d_out;
    char* ws = (char*)d_ws;

    _Float16* xhi  = (_Float16*)(ws + XHI_OFF);
    _Float16* xlo  = (_Float16*)(ws + XLO_OFF);
    float* candv   = (float*)(ws + CANDV_OFF);
    unsigned short* candi = (unsigned short*)(ws + CANDI_OFF);
    float* sq      = (float*)(ws + SQ_OFF);
    int*   knn     = (int*)  (ws + KNN_OFF);
    int*   deg     = (int*)  (ws + DEG_OFF);
    int*   cnt     = (int*)  (ws + CNT_OFF);
    float* dinv    = (float*)(ws + DINV_OFF);
    int*   row_ptr = (int*)  (ws + RPTR_OFF);
    int*   col     = (int*)  (ws + COL_OFF);
    _Float16* w1t  = (_Float16*)(ws + W1T_OFF);
    _Float16* w2t  = (_Float16*)(ws + W2T_OFF);
    float* hw      = (float*)(ws + HW_OFF);       // reuses xlo region (post-gram)
    _Float16* h1h  = (_Float16*)(ws + H1H_OFF);   // reuses xlo region (post-gram)

    conv_split_kernel<<<12544, 256, 0, stream>>>(x, xhi, xlo);
    sq_kernel<<<N_NODES, 64, 0, stream>>>(x, sq);
    wtrans_kernel<<<dim3(CDIM / 64, ODIM / 64), 256, 0, stream>>>(W1, w1t, CDIM, ODIM);
    wtrans_kernel<<<dim3(ODIM / 64, ODIM / 64), 256, 0, stream>>>(W2, w2t, ODIM, ODIM);

    gram_topk_mfma<<<GRID_G, 256, 0, stream>>>(xhi, xlo, sq, candv, candi);
    merge_topk_kernel<<<N_NODES / 4, 256, 0, stream>>>(candv, candi, knn);

    graph_init_kernel<<<(N_NODES + 255) / 256, 256, 0, stream>>>(deg, cnt);
    deg_count_kernel<<<(N_NODES * 8) / 256, 256, 0, stream>>>(knn, deg);
    dinv_kernel<<<(N_NODES + 255) / 256, 256, 0, stream>>>(deg, dinv);
    scan_kernel<<<1, 256, 0, stream>>>(deg, row_ptr);
    scatter_kernel<<<(N_NODES + 255) / 256, 256, 0, stream>>>(knn, row_ptr, cnt, col);

    hgemm_nt_kernel<<<(N_NODES / 128) * (ODIM / 128), 256, 0, stream>>>(xhi, w1t, hw, N_NODES, ODIM, CDIM);
    aggregate_kernel<true><<<N_NODES / 4, 256, 0, stream>>>(hw, row_ptr, col, dinv, b1, (void*)h1h);
    hgemm_nt_kernel<<<(N_NODES / 128) * (ODIM / 128), 256, 0, stream>>>(h1h, w2t, hw, N_NODES, ODIM, ODIM);
    aggregate_kernel<false><<<N_NODES / 4, 256, 0, stream>>>(hw, row_ptr, col, dinv, b2, (void*)out);
}